// Round 1
// 2081.102 us; speedup vs baseline: 1.1119x; 1.1119x over previous
//
#include <hip/hip_runtime.h>
#include <hip/hip_bf16.h>
#include <cstdint>

// Problem constants
#define HIDN  3072
#define NHEAD 24
#define HDIM  128
#define NTOK  4096      // B*L = 2*2048
#define N1    21504     // 3*HID + MLP
#define K1    3072
#define N2    3072
#define K2    15360     // HID + MLP

typedef short bf16x8 __attribute__((ext_vector_type(8)));
typedef float f32x4  __attribute__((ext_vector_type(4)));

__device__ __forceinline__ unsigned short f2bf(float f) {
  unsigned u = __builtin_bit_cast(unsigned, f);
  u += 0x7fffu + ((u >> 16) & 1u);       // round-to-nearest-even
  return (unsigned short)(u >> 16);
}

// async global->LDS, 16B per lane; LDS dest = wave-uniform base + lane*16
__device__ __forceinline__ void g2l16(const void* g, void* l) {
  __builtin_amdgcn_global_load_lds(
      (__attribute__((address_space(1))) void*)g,
      (__attribute__((address_space(3))) void*)l, 16, 0, 0);
}

// ---------------- K0: silu(vec) ----------------
__global__ __launch_bounds__(256) void silu_kernel(const float* __restrict__ vec,
                                                   float* __restrict__ sv) {
  int i = blockIdx.x * 256 + threadIdx.x;
  if (i < 2 * HIDN) { float v = vec[i]; sv[i] = v / (1.f + expf(-v)); }
}

// ---------------- K1a: modbuf = broadcast mod_b ----------------
__global__ __launch_bounds__(256) void mod_init_kernel(const float* __restrict__ mod_b,
                                                       float* __restrict__ modbuf) {
  int i = blockIdx.x * 256 + threadIdx.x;
  if (i < 9216) { float b = mod_b[i]; modbuf[i] = b; modbuf[9216 + i] = b; }
}

// ---------------- K1b: modbuf += silu(vec) @ mod_w (k-split, atomic) ----------------
__global__ __launch_bounds__(256) void mod_gemm_kernel(const float* __restrict__ sv,
                                                       const float* __restrict__ mod_w,
                                                       float* __restrict__ modbuf) {
  __shared__ float s0[768], s1[768];
  int t = threadIdx.x;
  int kbase = blockIdx.y * 768;
  for (int i = 0; i < 3; i++) {
    s0[t + i * 256] = sv[kbase + t + i * 256];
    s1[t + i * 256] = sv[HIDN + kbase + t + i * 256];
  }
  __syncthreads();
  int n = blockIdx.x * 256 + t;
  float a0 = 0.f, a1 = 0.f;
  for (int k = 0; k < 768; k++) {
    float w = mod_w[(size_t)(kbase + k) * 9216 + n];
    a0 += s0[k] * w;
    a1 += s1[k] * w;
  }
  atomicAdd(&modbuf[n], a0);
  atomicAdd(&modbuf[9216 + n], a1);
}

// ---------------- K2: x_mod = (1+scale)*LN(x) + shift  -> bf16 ----------------
__global__ __launch_bounds__(256) void ln_mod_kernel(const float* __restrict__ x,
                                                     const float* __restrict__ mod,
                                                     unsigned short* __restrict__ xmod) {
  int row = blockIdx.x;            // token index
  int b = row >> 11;
  const float* xr = x + (size_t)row * HIDN;
  float vals[12];
  float s = 0.f, sq = 0.f;
  for (int i = 0; i < 12; i++) {
    float v = xr[threadIdx.x + i * 256];
    vals[i] = v; s += v; sq += v * v;
  }
  for (int off = 32; off; off >>= 1) { s += __shfl_xor(s, off); sq += __shfl_xor(sq, off); }
  __shared__ float ss[4], ssq[4];
  int wv = threadIdx.x >> 6, ln = threadIdx.x & 63;
  if (ln == 0) { ss[wv] = s; ssq[wv] = sq; }
  __syncthreads();
  s = ss[0] + ss[1] + ss[2] + ss[3];
  sq = ssq[0] + ssq[1] + ssq[2] + ssq[3];
  float mu = s * (1.f / HIDN);
  float var = sq * (1.f / HIDN) - mu * mu;
  float rstd = rsqrtf(var + 1e-6f);
  const float* shiftp = mod + (size_t)b * 9216;
  const float* scalep = shiftp + HIDN;
  for (int i = 0; i < 12; i++) {
    int c = threadIdx.x + i * 256;
    float y = (vals[i] - mu) * rstd;
    y = (1.f + scalep[c]) * y + shiftp[c];
    xmod[(size_t)row * HIDN + c] = f2bf(y);
  }
}

// ---------------- K3: transpose + f32->bf16 convert (src RxC -> dst CxR) ----------------
__global__ __launch_bounds__(256) void transpose_convert(const float* __restrict__ src,
                                                         unsigned short* __restrict__ dst,
                                                         int R, int C) {
  __shared__ float tile[64][65];
  int r0 = blockIdx.y * 64, c0 = blockIdx.x * 64;
  int t = threadIdx.x;
  int lr = t >> 6, lc = t & 63;
  for (int i = 0; i < 16; i++)
    tile[lr + i * 4][lc] = src[(size_t)(r0 + lr + i * 4) * C + c0 + lc];
  __syncthreads();
  for (int i = 0; i < 16; i++) {
    int orow = lr + i * 4;   // source col within tile
    dst[(size_t)(c0 + orow) * R + r0 + lc] = f2bf(tile[lc][orow]);
  }
}

// ---------------- K4/K6: bf16 MFMA GEMM, 256x256 tile, 8-phase schedule ----------------
// m201-style template: BK=64 (2 K-halves of 32), 8 waves (2M x 4N), 512 threads,
// LDS = 2(dbuf) x 2(kh) x 256 x 32 bf16 per matrix = 128 KiB total.
// Per phase: {ds_read subtile | stage 1 half-tile (2 x global_load_lds/wave)} ->
// barrier -> lgkmcnt(0) -> setprio(1) 16xMFMA setprio(0) -> barrier.
// vmcnt(6) only at phases 4/8 (3 half-tiles stay in flight); last iter drains vmcnt(0).
// st_16x32 swizzle: global source chunk pre-swizzled, ds_read chunk XORed the same way.
// A: MxK row-major bf16, BT: NxK row-major bf16 (pre-transposed weight).
// MODE 0 (lin1): n<9216 -> qkv f32; else gelu -> concat bf16 at col n-6144
// MODE 1 (lin2): out = x + gate * (acc + bias)  (final output, f32)
template <int MODE, int KD>
__global__ __launch_bounds__(512, 2) void gemm_kernel(
    const unsigned short* __restrict__ A, const unsigned short* __restrict__ BT,
    const float* __restrict__ bias,
    float* __restrict__ out_qkv, unsigned short* __restrict__ out_cat,
    const float* __restrict__ x, const float* __restrict__ mod,
    float* __restrict__ out) {
  constexpr int nt = KD / 64;
  static_assert(nt % 2 == 0, "K must be multiple of 128");
  __shared__ unsigned short As[2][2][256][32];   // [dbuf][kh][row][k32]
  __shared__ unsigned short Bs[2][2][256][32];

  const int t = threadIdx.x;
  const int w = t >> 6, l = t & 63;
  const int wm = w >> 2, wn = w & 3;             // 2M x 4N wave grid
  const int r = l & 15, quad = l >> 4;
  // reader: lane quad wants global k-chunk 'quad'; stored at chunk quad ^ ((row>>3&1)<<1)
  const int koff = (quad ^ (((r >> 3) & 1) << 1)) * 8;
  // stager: lane covers (row = base + l>>2, lds chunk = l&3); read global chunk pre-swizzled
  const int srow = l >> 2;
  const int schunk = (l & 3) ^ (((l >> 5) & 1) << 1);

  // bijective XCD-aware block swizzle (both grids have nwg % 8 == 0)
  const int nwg = gridDim.x * gridDim.y;
  int bid = blockIdx.y * gridDim.x + blockIdx.x;
  bid = (bid & 7) * (nwg >> 3) + (bid >> 3);
  const int bx = bid % gridDim.x, by = bid / gridDim.x;
  const int m0 = by * 256, n0 = bx * 256;

  const unsigned short* Ab = A  + (size_t)(m0 + w * 32 + srow) * KD + schunk * 8;
  const unsigned short* Bb = BT + (size_t)(n0 + w * 32 + srow) * KD + schunk * 8;

  f32x4 acc[8][4];
#pragma unroll
  for (int i = 0; i < 8; ++i)
#pragma unroll
    for (int j = 0; j < 4; ++j) acc[i][j] = f32x4{0.f, 0.f, 0.f, 0.f};
  bf16x8 afr[4], bfr[4];

// stage one half-tile (mat, dbuf, k-half) of K-tile TILE: 2 x g2l16 per wave (32 rows)
#define STG(GB, LB, DB, KH, TILE) do { \
    _Pragma("unroll") for (int i = 0; i < 2; ++i) \
      g2l16((GB) + (size_t)i * 16 * KD + (TILE) * 64 + (KH) * 32, \
            &LB[DB][KH][w * 32 + i * 16][0]); \
  } while (0)
#define LDA(DB, KH, MQ) do { \
    _Pragma("unroll") for (int mf = 0; mf < 4; ++mf) \
      afr[mf] = *(const bf16x8*)&As[DB][KH][wm * 128 + ((MQ) * 4 + mf) * 16 + r][koff]; \
  } while (0)
#define LDB(DB, KH) do { \
    _Pragma("unroll") for (int nf = 0; nf < 4; ++nf) \
      bfr[nf] = *(const bf16x8*)&Bs[DB][KH][wn * 64 + nf * 16 + r][koff]; \
  } while (0)
#define MMA(MQ) do { \
    asm volatile("s_waitcnt lgkmcnt(0)" ::: "memory"); \
    __builtin_amdgcn_s_setprio(1); \
    _Pragma("unroll") for (int mf = 0; mf < 4; ++mf) \
      _Pragma("unroll") for (int nf = 0; nf < 4; ++nf) \
        acc[(MQ) * 4 + mf][nf] = __builtin_amdgcn_mfma_f32_16x16x32_bf16( \
            afr[mf], bfr[nf], acc[(MQ) * 4 + mf][nf], 0, 0, 0); \
    __builtin_amdgcn_s_setprio(0); \
  } while (0)
#define BAR() __builtin_amdgcn_s_barrier()
#define WAITV(N) asm volatile("s_waitcnt vmcnt(" #N ")" ::: "memory")

  // prologue: tile0 fully (db0), then 3 halves of tile1 (db1) left in flight
  STG(Bb, Bs, 0, 0, 0); STG(Ab, As, 0, 0, 0); STG(Bb, Bs, 0, 1, 0); STG(Ab, As, 0, 1, 0);
  WAITV(4);
  STG(Bb, Bs, 1, 0, 1); STG(Ab, As, 1, 0, 1); STG(Bb, Bs, 1, 1, 1);
  WAITV(6);
  BAR();

  // Stage/death schedule (per iteration over tiles T0->db0, T0+1->db1):
  // P0 stages T0+1 Ak1 (db1 Ak1 died prev P7);  P1: T0+2 Bk0 (db0 Bk0 died P0);
  // P2: T0+2 Ak0 (died P1); P3: T0+2 Bk1 (died P2) + vmcnt -> T0+1 resident;
  // P4: T0+2 Ak1 (died P3); P5: T0+3 Bk0 (db1 Bk0 died P4); P6: T0+3 Ak0 (died P5);
  // P7: T0+3 Bk1 (died P6) + vmcnt -> T0+2 resident.
#define ITER(T0, LAST) do { \
    /* P0: db0 kh0 mq0 */ \
    LDA(0, 0, 0); LDB(0, 0); \
    STG(Ab, As, 1, 1, (T0) + 1); \
    BAR(); MMA(0); BAR(); \
    /* P1: db0 kh0 mq1 */ \
    LDA(0, 0, 1); \
    if (!(LAST)) STG(Bb, Bs, 0, 0, (T0) + 2); \
    BAR(); MMA(1); BAR(); \
    /* P2: db0 kh1 mq0 */ \
    LDA(0, 1, 0); LDB(0, 1); \
    if (!(LAST)) STG(Ab, As, 0, 0, (T0) + 2); \
    BAR(); MMA(0); BAR(); \
    /* P3: db0 kh1 mq1 (tile boundary: ensure T0+1 resident) */ \
    LDA(0, 1, 1); \
    if (!(LAST)) STG(Bb, Bs, 0, 1, (T0) + 2); \
    if (LAST) { WAITV(0); } else { WAITV(6); } \
    BAR(); MMA(1); BAR(); \
    /* P4: db1 kh0 mq0 */ \
    LDA(1, 0, 0); LDB(1, 0); \
    if (!(LAST)) STG(Ab, As, 0, 1, (T0) + 2); \
    BAR(); MMA(0); BAR(); \
    /* P5: db1 kh0 mq1 */ \
    LDA(1, 0, 1); \
    if (!(LAST)) STG(Bb, Bs, 1, 0, (T0) + 3); \
    BAR(); MMA(1); BAR(); \
    /* P6: db1 kh1 mq0 */ \
    LDA(1, 1, 0); LDB(1, 1); \
    if (!(LAST)) STG(Ab, As, 1, 0, (T0) + 3); \
    BAR(); MMA(0); BAR(); \
    /* P7: db1 kh1 mq1 (tile boundary: ensure T0+2 resident) */ \
    LDA(1, 1, 1); \
    if (!(LAST)) STG(Bb, Bs, 1, 1, (T0) + 3); \
    if (LAST) { WAITV(0); } else { WAITV(6); } \
    BAR(); MMA(1); BAR(); \
  } while (0)

#pragma unroll 1
  for (int t0 = 0; t0 + 2 < nt; t0 += 2) ITER(t0, 0);
  ITER(nt - 2, 1);   // peeled: no prefetch, drain to vmcnt(0)

#undef ITER
#undef WAITV
#undef BAR
#undef MMA
#undef LDB
#undef LDA
#undef STG

  // epilogue: C/D layout col=lane&15, row=quad*4+reg (m89/m91 verified)
#pragma unroll
  for (int nf = 0; nf < 4; ++nf) {
    const int col = n0 + wn * 64 + nf * 16 + r;
    const float bv = bias[col];
#pragma unroll
    for (int mi = 0; mi < 8; ++mi) {
      const int rowb = m0 + wm * 128 + mi * 16 + quad * 4;
#pragma unroll
      for (int rr = 0; rr < 4; ++rr) {
        const int row = rowb + rr;
        float v = acc[mi][nf][rr] + bv;
        if (MODE == 0) {
          if (n0 < 9216) {
            out_qkv[(size_t)row * 9216 + col] = v;
          } else {
            float u = 0.7978845608028654f * (v + 0.044715f * v * v * v);
            float gl = 0.5f * v * (1.f + tanhf(u));
            out_cat[(size_t)row * 15360 + (col - 6144)] = f2bf(gl);
          }
        } else {
          const int bb = row >> 11;
          float res = x[(size_t)row * HIDN + col] + mod[(size_t)bb * 9216 + 6144 + col] * v;
          out[(size_t)row * HIDN + col] = res;
        }
      }
    }
  }
}

// ---------------- K5: per-token head-attention (24x24 scores per token) ----------------
// qkv row layout per token: [q(24x128) | k(24x128) | v(24x128)]
#define QROW 132   // 128 + 4 pad (keeps 16B alignment, spreads banks)
__global__ __launch_bounds__(256) void attn_kernel(const float* __restrict__ qkv,
                                                   const float* __restrict__ pe,
                                                   const float* __restrict__ q_scale,
                                                   const float* __restrict__ k_scale,
                                                   unsigned short* __restrict__ concat) {
  __shared__ float qs[3 * 24 * QROW];   // 38016 B
  __shared__ float sc[24 * 24];
  const int idx = blockIdx.x;           // token = b*2048 + l
  const int t = threadIdx.x;
  const float* src = qkv + (size_t)idx * 9216;

  // load q/k/v into padded LDS rows
  for (int i = 0; i < 9; i++) {
    int chunk = t + i * 256;            // 2304 float4 chunks
    float4 v = ((const float4*)src)[chunk];
    int e = chunk * 4;
    int s = e / 3072;
    int rem = e - s * 3072;
    int hh = rem >> 7, d = rem & 127;
    *(float4*)&qs[(s * 24 + hh) * QROW + d] = v;
  }
  __syncthreads();

  // rms_norm + rope on q and k rows (48 rows, 12 per wave; lane owns pair (2j,2j+1))
  const int wv = t >> 6, ln = t & 63;
  float4 pe4 = ((const float4*)pe)[(size_t)idx * 64 + ln];
  for (int j = 0; j < 12; j++) {
    int row = wv * 12 + j;              // 0..47
    int s = row / 24, hh = row % 24;
    float* rp = &qs[(s * 24 + hh) * QROW];
    float x0 = rp[2 * ln], x1 = rp[2 * ln + 1];
    float ssum = x0 * x0 + x1 * x1;
    for (int off = 32; off; off >>= 1) ssum += __shfl_xor(ssum, off);
    float rrms = rsqrtf(ssum * (1.f / 128.f) + 1e-6f);
    const float* scl = (s == 0) ? q_scale : k_scale;
    float y0 = x0 * rrms * scl[2 * ln];
    float y1 = x1 * rrms * scl[2 * ln + 1];
    rp[2 * ln]     = pe4.x * y0 + pe4.y * y1;
    rp[2 * ln + 1] = pe4.z * y0 + pe4.w * y1;
  }
  __syncthreads();

  // scores[h][g] = q_h . k_g / sqrt(128)
  for (int p = t; p < 576; p += 256) {
    int h = p / 24, g = p % 24;
    const float* qr = &qs[(0 * 24 + h) * QROW];
    const float* kr = &qs[(1 * 24 + g) * QROW];
    float a = 0.f;
    for (int d = 0; d < 128; d++) a += qr[d] * kr[d];
    sc[h * 24 + g] = a * 0.08838834764831845f;
  }
  __syncthreads();

  // softmax over g (one thread per row)
  if (t < 24) {
    float m = -1e30f;
    for (int g = 0; g < 24; g++) m = fmaxf(m, sc[t * 24 + g]);
    float sum = 0.f;
    for (int g = 0; g < 24; g++) { float e = expf(sc[t * 24 + g] - m); sc[t * 24 + g] = e; sum += e; }
    float inv = 1.f / sum;
    for (int g = 0; g < 24; g++) sc[t * 24 + g] *= inv;
  }
  __syncthreads();

  // attn[h][d] = sum_g probs[h][g] * v[g][d]  -> concat cols [0,3072) bf16
  for (int o = t; o < 3072; o += 256) {
    int h = o >> 7, d = o & 127;
    float a = 0.f;
    for (int g = 0; g < 24; g++) a += sc[h * 24 + g] * qs[(2 * 24 + g) * QROW + d];
    concat[(size_t)idx * 15360 + o] = f2bf(a);
  }
}

extern "C" void kernel_launch(void* const* d_in, const int* in_sizes, int n_in,
                              void* d_out, int out_size, void* d_ws, size_t ws_size,
                              hipStream_t stream) {
  const float* x       = (const float*)d_in[0];
  const float* vec     = (const float*)d_in[1];
  const float* pe      = (const float*)d_in[2];
  const float* mod_w   = (const float*)d_in[3];
  const float* mod_b   = (const float*)d_in[4];
  const float* lin1_w  = (const float*)d_in[5];
  const float* lin1_b  = (const float*)d_in[6];
  const float* lin2_w  = (const float*)d_in[7];
  const float* lin2_b  = (const float*)d_in[8];
  const float* q_scale = (const float*)d_in[9];
  const float* k_scale = (const float*)d_in[10];
  float* out = (float*)d_out;

  // workspace carve (all 256B-aligned)
  char* ws = (char*)d_ws;
  float* silu_v = (float*)ws;              ws += 24576;                 // 2*3072 f32
  float* modbuf = (float*)ws;              ws += 73728;                 // 2*9216 f32
  unsigned short* xmod = (unsigned short*)ws; ws += (size_t)NTOK * HIDN * 2;   // 25.2 MB
  unsigned short* w1t  = (unsigned short*)ws; ws += (size_t)N1 * K1 * 2;       // 132.1 MB
  unsigned short* w2t  = (unsigned short*)ws; ws += (size_t)N2 * K2 * 2;       // 94.4 MB
  float* qkvbuf = (float*)ws;              ws += (size_t)NTOK * 9216 * 4;      // 151.0 MB
  unsigned short* ccat = (unsigned short*)ws; ws += (size_t)NTOK * 15360 * 2;  // 125.8 MB

  silu_kernel<<<24, 256, 0, stream>>>(vec, silu_v);
  mod_init_kernel<<<36, 256, 0, stream>>>(mod_b, modbuf);
  mod_gemm_kernel<<<dim3(36, 4), 256, 0, stream>>>(silu_v, mod_w, modbuf);
  ln_mod_kernel<<<NTOK, 256, 0, stream>>>(x, modbuf, xmod);
  transpose_convert<<<dim3(N1 / 64, K1 / 64), 256, 0, stream>>>(lin1_w, w1t, K1, N1);
  transpose_convert<<<dim3(N2 / 64, K2 / 64), 256, 0, stream>>>(lin2_w, w2t, K2, N2);
  gemm_kernel<0, K1><<<dim3(N1 / 256, NTOK / 256), 512, 0, stream>>>(
      xmod, w1t, lin1_b, qkvbuf, ccat, nullptr, nullptr, nullptr);
  attn_kernel<<<NTOK, 256, 0, stream>>>(qkvbuf, pe, q_scale, k_scale, ccat);
  gemm_kernel<1, K2><<<dim3(N2 / 256, NTOK / 256), 512, 0, stream>>>(
      ccat, w2t, lin2_b, nullptr, nullptr, x, modbuf, out);
}